// Round 1
// baseline (459.668 us; speedup 1.0000x reference)
//
#include <hip/hip_runtime.h>

typedef __attribute__((ext_vector_type(8))) short bf16x8;
typedef __attribute__((ext_vector_type(4))) float f32x4;

#define HID 50
#define TSTEPS 512
#define LOG2E 1.4426950408889634f

static __device__ __forceinline__ short f2bf(float f) {
    unsigned u = __builtin_bit_cast(unsigned, f);
    u = (u + 0x7fffu + ((u >> 16) & 1u)) >> 16;   // RNE
    return (short)u;
}

static __device__ __forceinline__ float fexp2(float x) {
#if __has_builtin(__builtin_amdgcn_exp2f)
    return __builtin_amdgcn_exp2f(x);
#else
    return exp2f(x);
#endif
}
static __device__ __forceinline__ float frcp(float x) {
#if __has_builtin(__builtin_amdgcn_rcpf)
    return __builtin_amdgcn_rcpf(x);
#else
    return 1.0f / x;
#endif
}
static __device__ __forceinline__ float sigm(float x) {
    return frcp(1.0f + fexp2(-LOG2E * x));
}
static __device__ __forceinline__ float tanh_(float x) {
    return 1.0f - 2.0f * frcp(1.0f + fexp2(2.0f * LOG2E * x));
}

// One block = 16 batch rows, 4 waves. Wave w owns j-slice [w*16, w*16+16) of the
// (padded to 64) hidden dim, for ALL 4 gates -> i,f,g,o for a given (b,j) land in
// the same lane (C layout: col=lane&15 -> j, row=(lane>>4)*4+r -> b). Lane-local
// c/h update; h round-trips through a 2KB swizzled double-buffered LDS tile only.
__global__ __launch_bounds__(256) void lstm_fused(
    const float* __restrict__ seq,
    const float* __restrict__ W_ih,
    const float* __restrict__ W_hh,
    const float* __restrict__ b_ih,
    const float* __restrict__ b_hh,
    const float* __restrict__ W_out,
    const float* __restrict__ b_out,
    float* __restrict__ out)
{
    __shared__ __align__(16) short h_lds[2 * 16 * 64];  // bf16 bits, dbuf, XOR-swizzled rows of 128B
    __shared__ float h32[16][51];                       // final h staging (odd stride: no conflicts)

    const int tid = threadIdx.x;
    const int l   = tid & 63;
    const int wv  = tid >> 6;          // wave = j-slice 0..3
    const int l15 = l & 15;
    const int lq  = l >> 4;            // 0..3
    const int jl  = wv * 16 + l15;     // padded hidden col 0..63
    const bool jv = (jl < HID);
    const int rowbase = blockIdx.x << 4;
    const int swz = (l15 & 7) << 4;    // A-read swizzle (row = l15)

    // zero both h buffers (padded cols 50..63 stay zero forever)
    for (int i = tid; i < 2 * 16 * 64; i += 256) h_lds[i] = 0;

    // ---- B fragments: W_hh^T, padded [256][64], bf16, resident in VGPRs all 512 steps.
    // B-frag layout: lane holds col n=l&15 (within tile), k = 32*kk + 8*(l>>4) + e.
    bf16x8 Bf[4][2];
#pragma unroll
    for (int g = 0; g < 4; ++g)
#pragma unroll
        for (int kk = 0; kk < 2; ++kk) {
            bf16x8 v;
#pragma unroll
            for (int e = 0; e < 8; ++e) {
                int k = kk * 32 + lq * 8 + e;
                float val = (jv && k < HID) ? W_hh[(g * HID + jl) * HID + k] : 0.0f;
                v[e] = f2bf(val);
            }
            Bf[g][kk] = v;
        }

    // ---- W_ih rows + fused bias (fp32, cached in regs)
    float4 wih[4]; float bias[4];
#pragma unroll
    for (int g = 0; g < 4; ++g) {
        if (jv) {
            wih[g]  = *(const float4*)(W_ih + (g * HID + jl) * 4);
            bias[g] = b_ih[g * HID + jl] + b_hh[g * HID + jl];
        } else {
            wih[g] = make_float4(0.f, 0.f, 0.f, 0.f);
            bias[g] = 0.f;
        }
    }

    // ---- seq row pointers (lane covers rows lq*4 + r), 16B per step
    const char* sp[4];
#pragma unroll
    for (int r = 0; r < 4; ++r)
        sp[r] = (const char*)seq + (size_t)(rowbase + lq * 4 + r) * TSTEPS * 16;

    float c[4] = {0.f, 0.f, 0.f, 0.f};
    float h[4] = {0.f, 0.f, 0.f, 0.f};

    // distance-2 prefetch buffers (named: no runtime indexing -> stay in regs)
    float4 sqA[4], sqB[4];
#pragma unroll
    for (int r = 0; r < 4; ++r) sqA[r] = *(const float4*)(sp[r]);
#pragma unroll
    for (int r = 0; r < 4; ++r) sqB[r] = *(const float4*)(sp[r] + 16);

    __syncthreads();   // h_lds zeroed

    const char* hb = (const char*)h_lds;

    // One step: read A(prev h, buf RD) -> 8 MFMA -> fp32 x-part + activations ->
    // lane-local c/h update -> prefetch seq(t+2) -> write h bf16 to buf WR -> barrier.
    // Single barrier/step is safe: dbuf kills WAR, barrier orders RAW.
#define STEP(TT, SQ, RDOFF, WROFF)                                                             \
    {                                                                                          \
        bf16x8 a0 = *(const bf16x8*)(hb + (RDOFF) + l15 * 128 + ((lq * 16) ^ swz));            \
        bf16x8 a1 = *(const bf16x8*)(hb + (RDOFF) + l15 * 128 + ((64 + lq * 16) ^ swz));       \
        f32x4 ac0 = {0.f,0.f,0.f,0.f}, ac1 = {0.f,0.f,0.f,0.f};                                \
        f32x4 ac2 = {0.f,0.f,0.f,0.f}, ac3 = {0.f,0.f,0.f,0.f};                                \
        ac0 = __builtin_amdgcn_mfma_f32_16x16x32_bf16(a0, Bf[0][0], ac0, 0, 0, 0);             \
        ac1 = __builtin_amdgcn_mfma_f32_16x16x32_bf16(a0, Bf[1][0], ac1, 0, 0, 0);             \
        ac2 = __builtin_amdgcn_mfma_f32_16x16x32_bf16(a0, Bf[2][0], ac2, 0, 0, 0);             \
        ac3 = __builtin_amdgcn_mfma_f32_16x16x32_bf16(a0, Bf[3][0], ac3, 0, 0, 0);             \
        ac0 = __builtin_amdgcn_mfma_f32_16x16x32_bf16(a1, Bf[0][1], ac0, 0, 0, 0);             \
        ac1 = __builtin_amdgcn_mfma_f32_16x16x32_bf16(a1, Bf[1][1], ac1, 0, 0, 0);             \
        ac2 = __builtin_amdgcn_mfma_f32_16x16x32_bf16(a1, Bf[2][1], ac2, 0, 0, 0);             \
        ac3 = __builtin_amdgcn_mfma_f32_16x16x32_bf16(a1, Bf[3][1], ac3, 0, 0, 0);             \
        _Pragma("unroll")                                                                      \
        for (int r = 0; r < 4; ++r) {                                                          \
            float zi = ac0[r] + bias[0] + SQ[r].x*wih[0].x + SQ[r].y*wih[0].y                  \
                                        + SQ[r].z*wih[0].z + SQ[r].w*wih[0].w;                 \
            float zf = ac1[r] + bias[1] + SQ[r].x*wih[1].x + SQ[r].y*wih[1].y                  \
                                        + SQ[r].z*wih[1].z + SQ[r].w*wih[1].w;                 \
            float zg = ac2[r] + bias[2] + SQ[r].x*wih[2].x + SQ[r].y*wih[2].y                  \
                                        + SQ[r].z*wih[2].z + SQ[r].w*wih[2].w;                 \
            float zo = ac3[r] + bias[3] + SQ[r].x*wih[3].x + SQ[r].y*wih[3].y                  \
                                        + SQ[r].z*wih[3].z + SQ[r].w*wih[3].w;                 \
            float iv = sigm(zi), fv = sigm(zf), gv = tanh_(zg), ov = sigm(zo);                 \
            c[r] = fv * c[r] + iv * gv;                                                        \
            h[r] = ov * tanh_(c[r]);                                                           \
        }                                                                                      \
        if ((TT) + 2 < TSTEPS) {                                                               \
            _Pragma("unroll")                                                                  \
            for (int r = 0; r < 4; ++r)                                                        \
                SQ[r] = *(const float4*)(sp[r] + ((TT) + 2) * 16);                             \
        }                                                                                      \
        if (jv) {                                                                              \
            _Pragma("unroll")                                                                  \
            for (int r = 0; r < 4; ++r) {                                                      \
                int row = lq * 4 + r;                                                          \
                *(short*)((char*)h_lds + (WROFF) + row * 128 +                                 \
                          ((2 * jl) ^ ((row & 7) << 4))) = f2bf(h[r]);                         \
            }                                                                                  \
        }                                                                                      \
        __syncthreads();                                                                       \
    }

    for (int t = 0; t < TSTEPS; t += 2) {
        STEP(t,     sqA, 0,    2048);
        STEP(t + 1, sqB, 2048, 0);
    }
#undef STEP

    // ---- epilogue: out[b] = h_last[b,:] @ W_out + b_out (fp32 h from regs)
    if (jv) {
#pragma unroll
        for (int r = 0; r < 4; ++r) h32[lq * 4 + r][jl] = h[r];
    }
    __syncthreads();
    if (tid < 16) {
        float s = b_out[0];
        for (int j = 0; j < HID; ++j) s += h32[tid][j] * W_out[j];
        out[rowbase + tid] = s;
    }
}

extern "C" void kernel_launch(void* const* d_in, const int* in_sizes, int n_in,
                              void* d_out, int out_size, void* d_ws, size_t ws_size,
                              hipStream_t stream) {
    const float* seq   = (const float*)d_in[0];
    const float* W_ih  = (const float*)d_in[1];
    const float* W_hh  = (const float*)d_in[2];
    const float* b_ih  = (const float*)d_in[3];
    const float* b_hh  = (const float*)d_in[4];
    const float* W_out = (const float*)d_in[5];
    const float* b_out = (const float*)d_in[6];
    float* out = (float*)d_out;

    const int B = in_sizes[0] / (TSTEPS * 4);   // 4096
    lstm_fused<<<dim3(B / 16), dim3(256), 0, stream>>>(
        seq, W_ih, W_hh, b_ih, b_hh, W_out, b_out, out);
}

// Round 3
// 348.469 us; speedup vs baseline: 1.3191x; 1.3191x over previous
//
#include <hip/hip_runtime.h>

typedef __attribute__((ext_vector_type(8))) short bf16x8;
typedef __attribute__((ext_vector_type(4))) float f32x4;

#define HID 50
#define TSTEPS 512
#define LOG2E 1.4426950408889634f

static __device__ __forceinline__ short f2bf(float f) {
    unsigned u = __builtin_bit_cast(unsigned, f);
    u = (u + 0x7fffu + ((u >> 16) & 1u)) >> 16;   // RNE
    return (short)u;
}

static __device__ __forceinline__ float fexp2(float x) {
#if __has_builtin(__builtin_amdgcn_exp2f)
    return __builtin_amdgcn_exp2f(x);
#else
    return exp2f(x);
#endif
}
static __device__ __forceinline__ float frcp(float x) {
#if __has_builtin(__builtin_amdgcn_rcpf)
    return __builtin_amdgcn_rcpf(x);
#else
    return 1.0f / x;
#endif
}
static __device__ __forceinline__ float sigm(float x) {
    return frcp(1.0f + fexp2(-LOG2E * x));
}
static __device__ __forceinline__ float tanh_(float x) {
    return 1.0f - 2.0f * frcp(1.0f + fexp2(2.0f * LOG2E * x));
}

// One block = 16 batch rows, 4 waves. Wave w owns j-slice [w*16, w*16+16) of the
// (padded to 64) hidden dim, for ALL 4 gates -> i,f,g,o for a given (b,j) land in
// the same lane. Lane-local c/h update; h round-trips through a 2KB swizzled
// double-buffered LDS tile.
//
// R2: the full gate pre-activation is ONE K=64 MFMA pair:
//   A row b = [ h[b][0..49] | x[b][t][0..3] | 1.0 | 0.. ]   (k=50..53 x, k=54 bias)
//   B col j = [ W_hh[g*H+j][0..49] | W_ih[g*H+j][0..3] | bias_g[j] | 0.. ]
// x+1.0 are injected IN-REGISTER into the a1 fragment by the lq==2 lanes
// (k=48..55 slice), so LDS keeps holding only h (cols 50..63 stay zero).
__global__ __launch_bounds__(256) void lstm_fused(
    const float* __restrict__ seq,
    const float* __restrict__ W_ih,
    const float* __restrict__ W_hh,
    const float* __restrict__ b_ih,
    const float* __restrict__ b_hh,
    const float* __restrict__ W_out,
    const float* __restrict__ b_out,
    float* __restrict__ out)
{
    __shared__ __align__(16) short h_lds[2 * 16 * 64];  // bf16 bits, dbuf, XOR-swizzled rows of 128B
    __shared__ float h32[16][51];                       // final h staging (odd stride: no conflicts)

    const int tid = threadIdx.x;
    const int l   = tid & 63;
    const int wv  = tid >> 6;          // wave = j-slice 0..3
    const int l15 = l & 15;
    const int lq  = l >> 4;            // 0..3
    const int jl  = wv * 16 + l15;     // padded hidden col 0..63
    const bool jv = (jl < HID);
    const int rowbase = blockIdx.x << 4;
    const int swz = (l15 & 7) << 4;    // A-read swizzle (row = l15)

    // zero both h buffers (padded cols 50..63 stay zero forever)
    for (int i = tid; i < 2 * 16 * 64; i += 256) h_lds[i] = 0;

    // ---- B fragments: [W_hh^T | W_ih^T | bias] padded [64 k][64 j], bf16,
    // resident in VGPRs all 512 steps. Lane holds col jl, k = kk*32 + lq*8 + e.
    bf16x8 Bf[4][2];
#pragma unroll
    for (int g = 0; g < 4; ++g)
#pragma unroll
        for (int kk = 0; kk < 2; ++kk) {
            bf16x8 v;
#pragma unroll
            for (int e = 0; e < 8; ++e) {
                int k = kk * 32 + lq * 8 + e;
                float val = 0.0f;
                if (jv) {
                    if (k < HID)            val = W_hh[(g * HID + jl) * HID + k];
                    else if (k < HID + 4)   val = W_ih[(g * HID + jl) * 4 + (k - HID)];
                    else if (k == HID + 4)  val = b_ih[g * HID + jl] + b_hh[g * HID + jl];
                }
                v[e] = f2bf(val);
            }
            Bf[g][kk] = v;
        }

    // ---- x prefetch: only lq==2 lanes feed x into the MFMA (k=48..55 slice).
    // Lane covers batch row l15; one float4 (x[t][0..4]) per step, distance-2.
    const char* xp = (const char*)seq + (size_t)(rowbase + l15) * TSTEPS * 16;
    float4 sqA = make_float4(0.f, 0.f, 0.f, 0.f);
    float4 sqB = make_float4(0.f, 0.f, 0.f, 0.f);
    if (lq == 2) {
        sqA = *(const float4*)(xp);
        sqB = *(const float4*)(xp + 16);
    }

    float c[4] = {0.f, 0.f, 0.f, 0.f};
    float h[4] = {0.f, 0.f, 0.f, 0.f};

    __syncthreads();   // h_lds zeroed

    const char* hb = (const char*)h_lds;

    // One step: read A(prev h, buf RD) -> inject x/1.0 (lq==2) -> 8 MFMA ->
    // activations -> lane-local c/h update -> prefetch x(t+2) -> write h bf16
    // to buf WR -> barrier. Dbuf kills WAR, barrier orders RAW.
#define STEP(TT, SQ, RDOFF, WROFF)                                                             \
    {                                                                                          \
        bf16x8 a0 = *(const bf16x8*)(hb + (RDOFF) + l15 * 128 + ((lq * 16) ^ swz));            \
        bf16x8 a1 = *(const bf16x8*)(hb + (RDOFF) + l15 * 128 + ((64 + lq * 16) ^ swz));       \
        if (lq == 2) {                                                                         \
            a1[2] = f2bf(SQ.x); a1[3] = f2bf(SQ.y);                                            \
            a1[4] = f2bf(SQ.z); a1[5] = f2bf(SQ.w);                                            \
            a1[6] = (short)0x3f80;  /* 1.0 -> bias row */                                      \
        }                                                                                      \
        f32x4 ac0 = {0.f,0.f,0.f,0.f}, ac1 = {0.f,0.f,0.f,0.f};                                \
        f32x4 ac2 = {0.f,0.f,0.f,0.f}, ac3 = {0.f,0.f,0.f,0.f};                                \
        ac0 = __builtin_amdgcn_mfma_f32_16x16x32_bf16(a0, Bf[0][0], ac0, 0, 0, 0);             \
        ac1 = __builtin_amdgcn_mfma_f32_16x16x32_bf16(a0, Bf[1][0], ac1, 0, 0, 0);             \
        ac2 = __builtin_amdgcn_mfma_f32_16x16x32_bf16(a0, Bf[2][0], ac2, 0, 0, 0);             \
        ac3 = __builtin_amdgcn_mfma_f32_16x16x32_bf16(a0, Bf[3][0], ac3, 0, 0, 0);             \
        ac0 = __builtin_amdgcn_mfma_f32_16x16x32_bf16(a1, Bf[0][1], ac0, 0, 0, 0);             \
        ac1 = __builtin_amdgcn_mfma_f32_16x16x32_bf16(a1, Bf[1][1], ac1, 0, 0, 0);             \
        ac2 = __builtin_amdgcn_mfma_f32_16x16x32_bf16(a1, Bf[2][1], ac2, 0, 0, 0);             \
        ac3 = __builtin_amdgcn_mfma_f32_16x16x32_bf16(a1, Bf[3][1], ac3, 0, 0, 0);             \
        _Pragma("unroll")                                                                      \
        for (int r = 0; r < 4; ++r) {                                                          \
            float iv = sigm(ac0[r]), fv = sigm(ac1[r]);                                        \
            float gv = tanh_(ac2[r]), ov = sigm(ac3[r]);                                       \
            c[r] = fv * c[r] + iv * gv;                                                        \
            h[r] = ov * tanh_(c[r]);                                                           \
        }                                                                                      \
        if ((TT) + 2 < TSTEPS && lq == 2)                                                      \
            SQ = *(const float4*)(xp + ((TT) + 2) * 16);                                       \
        if (jv) {                                                                              \
            _Pragma("unroll")                                                                  \
            for (int r = 0; r < 4; ++r) {                                                      \
                int row = lq * 4 + r;                                                          \
                *(short*)((char*)h_lds + (WROFF) + row * 128 +                                 \
                          ((2 * jl) ^ ((row & 7) << 4))) = f2bf(h[r]);                         \
            }                                                                                  \
        }                                                                                      \
        __syncthreads();                                                                       \
    }

    for (int t = 0; t < TSTEPS; t += 2) {
        STEP(t,     sqA, 0,    2048);
        STEP(t + 1, sqB, 2048, 0);
    }
#undef STEP

    // ---- epilogue: out[b] = h_last[b,:] @ W_out + b_out (fp32 h from regs)
    if (jv) {
#pragma unroll
        for (int r = 0; r < 4; ++r) h32[lq * 4 + r][jl] = h[r];
    }
    __syncthreads();
    if (tid < 16) {
        float s = b_out[0];
        for (int j = 0; j < HID; ++j) s += h32[tid][j] * W_out[j];
        out[rowbase + tid] = s;
    }
}

extern "C" void kernel_launch(void* const* d_in, const int* in_sizes, int n_in,
                              void* d_out, int out_size, void* d_ws, size_t ws_size,
                              hipStream_t stream) {
    const float* seq   = (const float*)d_in[0];
    const float* W_ih  = (const float*)d_in[1];
    const float* W_hh  = (const float*)d_in[2];
    const float* b_ih  = (const float*)d_in[3];
    const float* b_hh  = (const float*)d_in[4];
    const float* W_out = (const float*)d_in[5];
    const float* b_out = (const float*)d_in[6];
    float* out = (float*)d_out;

    const int B = in_sizes[0] / (TSTEPS * 4);   // 4096
    lstm_fused<<<dim3(B / 16), dim3(256), 0, stream>>>(
        seq, W_ih, W_hh, b_ih, b_hh, W_out, b_out, out);
}

// Round 6
// 347.008 us; speedup vs baseline: 1.3247x; 1.0042x over previous
//
#include <hip/hip_runtime.h>

typedef __attribute__((ext_vector_type(8))) short bf16x8;
typedef __attribute__((ext_vector_type(4))) float f32x4;

#define HID 50
#define TSTEPS 512
#define LOG2E 1.4426950408889634f

static __device__ __forceinline__ short f2bf(float f) {
    unsigned u = __builtin_bit_cast(unsigned, f);
    u = (u + 0x7fffu + ((u >> 16) & 1u)) >> 16;   // RNE
    return (short)u;
}

static __device__ __forceinline__ float fexp2(float x) {
#if __has_builtin(__builtin_amdgcn_exp2f)
    return __builtin_amdgcn_exp2f(x);
#else
    return exp2f(x);
#endif
}
static __device__ __forceinline__ float frcp(float x) {
#if __has_builtin(__builtin_amdgcn_rcpf)
    return __builtin_amdgcn_rcpf(x);
#else
    return 1.0f / x;
#endif
}
static __device__ __forceinline__ float sigm(float x) {
    return frcp(1.0f + fexp2(-LOG2E * x));
}
static __device__ __forceinline__ float tanh_(float x) {
    return 1.0f - 2.0f * frcp(1.0f + fexp2(2.0f * LOG2E * x));
}

// LDS-write-only barrier: drain lgkmcnt (our ds_writes) but leave global
// x-prefetch loads IN FLIGHT across the barrier (T4; __syncthreads would
// emit s_waitcnt vmcnt(0) and serialize the prefetch latency every step).
// "memory" clobber keeps ds_writes above; sched_barrier(0) fences scheduling
// (rule 18); s_barrier itself is convergent.
static __device__ __forceinline__ void lds_barrier() {
    asm volatile("s_waitcnt lgkmcnt(0)" ::: "memory");
    __builtin_amdgcn_sched_barrier(0);
    __builtin_amdgcn_s_barrier();
}

// One block = 16 batch rows, 4 waves. Wave w owns j-slice [w*16,w*16+16) of the
// padded-64 hidden dim for ALL 4 gates -> i,f,g,o of a given (b,j) in one lane.
// Gate pre-activation is ONE K=64 MFMA pair:
//   A row b = [ h[b][0..49] | x[b][t][0..3] | 1.0 | 0.. ]
//   B col j = [ W_hh[g][j][:] | W_ih[g][j][:] | bias_g[j] | 0.. ]  (VGPR-resident)
// x+1.0 injected in-register into a1 by lq==2 lanes. h round-trips through a
// 2KB swizzled double-buffered LDS tile; 1 lgkm-only barrier per step.
__global__ __launch_bounds__(256) void lstm_fused(
    const float* __restrict__ seq,
    const float* __restrict__ W_ih,
    const float* __restrict__ W_hh,
    const float* __restrict__ b_ih,
    const float* __restrict__ b_hh,
    const float* __restrict__ W_out,
    const float* __restrict__ b_out,
    float* __restrict__ out)
{
    __shared__ __align__(16) short h_lds[2 * 16 * 64];  // bf16 bits, dbuf, XOR-swizzled rows of 128B
    __shared__ float h32[16][51];                       // final h staging

    const int tid = threadIdx.x;
    const int l   = tid & 63;
    const int wv  = tid >> 6;          // wave = j-slice 0..3
    const int l15 = l & 15;
    const int lq  = l >> 4;            // 0..3
    const int jl  = wv * 16 + l15;     // padded hidden col 0..63
    const bool jv = (jl < HID);
    const int rowbase = blockIdx.x << 4;
    const int swz = (l15 & 7) << 4;    // A-read swizzle (row = l15)

    for (int i = tid; i < 2 * 16 * 64; i += 256) h_lds[i] = 0;

    // ---- B fragments: [W_hh^T | W_ih^T | bias], bf16, VGPR-resident all 512 steps.
    bf16x8 Bf[4][2];
#pragma unroll
    for (int g = 0; g < 4; ++g)
#pragma unroll
        for (int kk = 0; kk < 2; ++kk) {
            bf16x8 v;
#pragma unroll
            for (int e = 0; e < 8; ++e) {
                int k = kk * 32 + lq * 8 + e;
                float val = 0.0f;
                if (jv) {
                    if (k < HID)            val = W_hh[(g * HID + jl) * HID + k];
                    else if (k < HID + 4)   val = W_ih[(g * HID + jl) * 4 + (k - HID)];
                    else if (k == HID + 4)  val = b_ih[g * HID + jl] + b_hh[g * HID + jl];
                }
                v[e] = f2bf(val);
            }
            Bf[g][kk] = v;
        }

    // ---- x prefetch: only lq==2 lanes feed x (k=48..55 A-slice). Distance-2.
    const char* xp = (const char*)seq + (size_t)(rowbase + l15) * TSTEPS * 16;
    float4 sqA = make_float4(0.f, 0.f, 0.f, 0.f);
    float4 sqB = make_float4(0.f, 0.f, 0.f, 0.f);
    if (lq == 2) {
        sqA = *(const float4*)(xp);
        sqB = *(const float4*)(xp + 16);
    }

    float c[4] = {0.f, 0.f, 0.f, 0.f};
    float h[4] = {0.f, 0.f, 0.f, 0.f};

    // ---- loop-invariant LDS addresses (RD/WR offsets 0/2048 fold into ds imm)
    const char* rdA = (const char*)h_lds + l15 * 128 + ((lq * 16) ^ swz);
    const char* rdB = (const char*)h_lds + l15 * 128 + ((64 + lq * 16) ^ swz);
    char* wb[4];
#pragma unroll
    for (int r = 0; r < 4; ++r) {
        int row = lq * 4 + r;
        wb[r] = (char*)h_lds + row * 128 + ((2 * jl) ^ ((row & 7) << 4));
    }

    __syncthreads();   // h_lds zeroed (full sync once is fine)

    // One step: read A(prev h) -> inject x/1.0 -> issue t+2 prefetch -> 8 MFMA ->
    // activations -> lane-local c/h update -> write h bf16 -> lgkm-only barrier.
#define STEP(TT, SQ, RDOFF, WROFF)                                                             \
    {                                                                                          \
        bf16x8 a0 = *(const bf16x8*)(rdA + (RDOFF));                                           \
        bf16x8 a1 = *(const bf16x8*)(rdB + (RDOFF));                                           \
        if (lq == 2) {                                                                         \
            a1[2] = f2bf(SQ.x); a1[3] = f2bf(SQ.y);                                            \
            a1[4] = f2bf(SQ.z); a1[5] = f2bf(SQ.w);                                            \
            a1[6] = (short)0x3f80;  /* 1.0 -> bias row */                                      \
        }                                                                                      \
        if ((TT) + 2 < TSTEPS && lq == 2)                                                      \
            SQ = *(const float4*)(xp + ((TT) + 2) * 16);  /* stays in flight across barriers */\
        f32x4 ac0 = {0.f,0.f,0.f,0.f}, ac1 = {0.f,0.f,0.f,0.f};                                \
        f32x4 ac2 = {0.f,0.f,0.f,0.f}, ac3 = {0.f,0.f,0.f,0.f};                                \
        ac0 = __builtin_amdgcn_mfma_f32_16x16x32_bf16(a0, Bf[0][0], ac0, 0, 0, 0);             \
        ac1 = __builtin_amdgcn_mfma_f32_16x16x32_bf16(a0, Bf[1][0], ac1, 0, 0, 0);             \
        ac2 = __builtin_amdgcn_mfma_f32_16x16x32_bf16(a0, Bf[2][0], ac2, 0, 0, 0);             \
        ac3 = __builtin_amdgcn_mfma_f32_16x16x32_bf16(a0, Bf[3][0], ac3, 0, 0, 0);             \
        ac0 = __builtin_amdgcn_mfma_f32_16x16x32_bf16(a1, Bf[0][1], ac0, 0, 0, 0);             \
        ac1 = __builtin_amdgcn_mfma_f32_16x16x32_bf16(a1, Bf[1][1], ac1, 0, 0, 0);             \
        ac2 = __builtin_amdgcn_mfma_f32_16x16x32_bf16(a1, Bf[2][1], ac2, 0, 0, 0);             \
        ac3 = __builtin_amdgcn_mfma_f32_16x16x32_bf16(a1, Bf[3][1], ac3, 0, 0, 0);             \
        _Pragma("unroll")                                                                      \
        for (int r = 0; r < 4; ++r) {                                                          \
            float iv = sigm(ac0[r]), fv = sigm(ac1[r]);                                        \
            float gv = tanh_(ac2[r]), ov = sigm(ac3[r]);                                       \
            c[r] = fv * c[r] + iv * gv;                                                        \
            h[r] = ov * tanh_(c[r]);                                                           \
        }                                                                                      \
        if (jv) {                                                                              \
            _Pragma("unroll")                                                                  \
            for (int r = 0; r < 4; ++r)                                                        \
                *(short*)(wb[r] + (WROFF)) = f2bf(h[r]);                                       \
        }                                                                                      \
        lds_barrier();                                                                         \
    }

    for (int t = 0; t < TSTEPS; t += 2) {
        STEP(t,     sqA, 0,    2048);
        STEP(t + 1, sqB, 2048, 0);
    }
#undef STEP

    // ---- epilogue: out[b] = h_last[b,:] @ W_out + b_out (fp32 h from regs)
    if (jv) {
#pragma unroll
        for (int r = 0; r < 4; ++r) h32[lq * 4 + r][jl] = h[r];
    }
    __syncthreads();
    if (tid < 16) {
        float s = b_out[0];
        for (int j = 0; j < HID; ++j) s += h32[tid][j] * W_out[j];
        out[rowbase + tid] = s;
    }
}

extern "C" void kernel_launch(void* const* d_in, const int* in_sizes, int n_in,
                              void* d_out, int out_size, void* d_ws, size_t ws_size,
                              hipStream_t stream) {
    const float* seq   = (const float*)d_in[0];
    const float* W_ih  = (const float*)d_in[1];
    const float* W_hh  = (const float*)d_in[2];
    const float* b_ih  = (const float*)d_in[3];
    const float* b_hh  = (const float*)d_in[4];
    const float* W_out = (const float*)d_in[5];
    const float* b_out = (const float*)d_in[6];
    float* out = (float*)d_out;

    const int B = in_sizes[0] / (TSTEPS * 4);   // 4096
    lstm_fused<<<dim3(B / 16), dim3(256), 0, stream>>>(
        seq, W_ih, W_hh, b_ih, b_hh, W_out, b_out, out);
}